// Round 2
// baseline (1215.117 us; speedup 1.0000x reference)
//
#include <hip/hip_runtime.h>
#include <cmath>

#define T_STEPS 1000
#define B_SZ    128
#define N_IN    85
#define N_RNN   512
#define N_OUT   33
#define K_PAD   88                      // 85 padded to 88 for float4
#define Y_SIZE  (T_STEPS * B_SZ * N_OUT)   // 4,224,000 floats

// ---------------------------------------------------------------------------
// K0: zero the diag-flag (lives at d_out[0], y-region, overwritten by head)
__global__ void k_zero_flag(int* flag) {
    if (threadIdx.x == 0 && blockIdx.x == 0) *flag = 0;
}

// ---------------------------------------------------------------------------
// K1: verify W_rec (rows 85..596 of W) is diagonal; set flag if not.
__global__ void k_check_diag(const float* __restrict__ W, int* flag) {
    const float* Wr = W + N_IN * N_RNN;
    bool bad = false;
    for (int i = blockIdx.x * blockDim.x + threadIdx.x;
         i < N_RNN * N_RNN; i += gridDim.x * blockDim.x) {
        int r = i >> 9, c = i & (N_RNN - 1);
        float v = Wr[i];
        if (r != c && v != 0.0f) bad = true;
    }
    if (bad) atomicOr(flag, 1);
}

// ---------------------------------------------------------------------------
__device__ __forceinline__ float softplus_f(float g) {
    return fmaxf(g, 0.0f) + __logf(1.0f + __expf(-fabsf(g)));
}

// ---------------------------------------------------------------------------
// K2-fused v2: diagonal-W_rec scan with fused input GEMM, TWO chains/thread.
// 512 blocks x 64 threads (single-wave blocks, 2 waves/CU). Thread owns
// (b, n) and (b, n+64): each broadcast ds_read_b128 of the x row now feeds
// 8 FMAs (was 4) -> LDS pipe demand per CU per step halves. Single-wave
// blocks need NO s_barrier; XST->read visibility is lgkmcnt(0) only, so
// the global prefetch queue (noise ring + x tile) is never drained.
__global__ __launch_bounds__(64, 1) void k_scan_fused(
        const float* __restrict__ x, const float* __restrict__ W,
        const float* __restrict__ bias, const float* __restrict__ noise,
        float* __restrict__ H, const int* __restrict__ flag) {
    if (*flag != 0) return;                    // general path handles it
    const int tid = threadIdx.x;               // 0..63
    const int b   = blockIdx.x >> 2;                   // 0..127
    const int q   = blockIdx.x & 3;
    const int n0  = (q << 7) + tid;                    // chain A column
    const int n1  = n0 + 64;                           // chain B column

    // W_in columns n0, n1 into registers; pads zero (0*garbage -> NaN risk).
    float w0[K_PAD], w1[K_PAD];
    #pragma unroll
    for (int k = 0; k < N_IN; ++k) {
        w0[k] = W[k * N_RNN + n0];
        w1[k] = W[k * N_RNN + n1];
    }
    w0[85] = w0[86] = w0[87] = 0.f;
    w1[85] = w1[86] = w1[87] = 0.f;
    const float d0 = W[(N_IN + n0) * N_RNN + n0];
    const float d1 = W[(N_IN + n1) * N_RNN + n1];
    const float b0 = bias[n0];
    const float b1 = bias[n1];

    __shared__ __align__(16) float xs[2][8][K_PAD];    // 5632 B double buffer
    const int row = tid >> 3;      // 0..7   (t-row within 8-step tile)
    const int l8  = tid & 7;       // 8 threads cooperate per row

    const size_t strT = (size_t)B_SZ * N_RNN;          // 65536
    const float* npA = noise + (size_t)b * N_RNN + n0;
    const float* npB = npA + 64;
    float*       hpA = H     + (size_t)b * N_RNN + n0;
    float*       hpB = hpA + 64;

    float rA0[8], rA1[8], rB0[8], rB1[8], xr[11];
    float h0 = 0.0f, h1 = 0.0f;

    // cooperative x-row load for the tile starting at t0 (into regs)
    // k = l8 + 8*j covers 0..87 exactly; only j=10 can exceed N_IN-1.
    auto XLD = [&](int t0) {
        int t = t0 + row;
        if (t > T_STEPS - 1) t = T_STEPS - 1;          // clamp: value unused
        const float* xrow = x + ((size_t)t * B_SZ + b) * N_IN;
        #pragma unroll
        for (int j = 0; j < 10; ++j) xr[j] = xrow[l8 + 8 * j];
        xr[10] = (l8 < 5) ? xrow[80 + l8] : 0.0f;      // k=85..87 pad
    };
    auto XST = [&](int buf) {
        #pragma unroll
        for (int j = 0; j < 11; ++j) xs[buf][row][l8 + 8 * j] = xr[j];
    };
    auto pref8 = [&](float (&r0)[8], float (&r1)[8], int t0) {
        #pragma unroll
        for (int u = 0; u < 8; ++u) {
            r0[u] = npA[(size_t)(t0 + u) * strT];
            r1[u] = npB[(size_t)(t0 + u) * strT];
        }
    };
    auto consume8 = [&](float (&r0)[8], float (&r1)[8], int t0, int buf) {
        #pragma unroll
        for (int u = 0; u < 8; ++u) {
            const float4* xv4 = (const float4*)(&xs[buf][u][0]);
            float a0 = 0.f, a1 = 0.f, a2 = 0.f, a3 = 0.f;   // chain A
            float c0 = 0.f, c1 = 0.f, c2 = 0.f, c3 = 0.f;   // chain B
            #pragma unroll
            for (int k4 = 0; k4 < K_PAD / 4; ++k4) {
                const float4 xv = xv4[k4];                  // LDS broadcast
                a0 = fmaf(xv.x, w0[4 * k4 + 0], a0);
                a1 = fmaf(xv.y, w0[4 * k4 + 1], a1);
                a2 = fmaf(xv.z, w0[4 * k4 + 2], a2);
                a3 = fmaf(xv.w, w0[4 * k4 + 3], a3);
                c0 = fmaf(xv.x, w1[4 * k4 + 0], c0);
                c1 = fmaf(xv.y, w1[4 * k4 + 1], c1);
                c2 = fmaf(xv.z, w1[4 * k4 + 2], c2);
                c3 = fmaf(xv.w, w1[4 * k4 + 3], c3);
            }
            const float g0 = ((a0 + a1) + (a2 + a3)) + (b0 + r0[u]) + d0 * h0;
            const float g1 = ((c0 + c1) + (c2 + c3)) + (b1 + r1[u]) + d1 * h1;
            h0 = 0.8f * h0 + 0.2f * softplus_f(g0);
            h1 = 0.8f * h1 + 0.2f * softplus_f(g1);
            hpA[(size_t)(t0 + u) * strT] = h0;
            hpB[(size_t)(t0 + u) * strT] = h1;
        }
    };

    // ---- prologue: noise tile 0 -> rA; x tile 0 -> LDS[0]; x tile 1 -> regs
    pref8(rA0, rA1, 0);
    XLD(0); XST(0);
    XLD(8);
    asm volatile("s_waitcnt lgkmcnt(0)" ::: "memory");
    __builtin_amdgcn_sched_barrier(0);

    int cur = 0;
    // tiles 0..123 in pairs (static ring parity: even->rA, odd->rB)
    #pragma unroll 1
    for (int tb2 = 0; tb2 < 62; ++tb2) {
        const int bb = tb2 << 1;
        // -- even tile bb: consume rA / xs[cur]; prefetch noise bb+1, x bb+2
        pref8(rB0, rB1, (bb + 1) << 3);
        consume8(rA0, rA1, bb << 3, cur);
        XST(cur ^ 1);                         // stage x tile bb+1
        XLD((bb + 2) << 3);                   // issue x loads tile bb+2
        asm volatile("s_waitcnt lgkmcnt(0)" ::: "memory");
        __builtin_amdgcn_sched_barrier(0);
        cur ^= 1;
        // -- odd tile bb+1: consume rB / xs[cur]; prefetch noise bb+2, x bb+3
        pref8(rA0, rA1, (bb + 2) << 3);       // max t0 = 124*8 = 992, valid
        consume8(rB0, rB1, (bb + 1) << 3, cur);
        XST(cur ^ 1);
        XLD((bb + 3) << 3);                   // clamped: tile 125/126 unused
        asm volatile("s_waitcnt lgkmcnt(0)" ::: "memory");
        __builtin_amdgcn_sched_barrier(0);
        cur ^= 1;
    }
    // ---- final tile 124 (even -> rA), t = 992..999, no prefetch
    consume8(rA0, rA1, 992, cur);
}

// ---------------------------------------------------------------------------
// K2b: G precompute — ONLY for the general (non-diagonal W_rec) fallback.
__global__ __launch_bounds__(256) void k_precompute(
        const float* __restrict__ x, const float* __restrict__ W,
        const float* __restrict__ bias, const float* __restrict__ noise,
        float* __restrict__ G, const int* __restrict__ flag) {
    if (*flag == 0) return;                 // fused fast path covers diag W
    __shared__ float xsh[128 * K_PAD];      // 45,056 B
    const int tid = threadIdx.x;
    const int n   = ((blockIdx.x & 1) << 8) + tid;
    const int r0  = (blockIdx.x >> 1) << 7;

    float wcol[K_PAD];
    #pragma unroll
    for (int k = 0; k < N_IN; ++k) wcol[k] = W[k * N_RNN + n];
    wcol[85] = 0.f; wcol[86] = 0.f; wcol[87] = 0.f;

    const float* xsrc = x + (size_t)r0 * N_IN;
    for (int i = tid; i < 128 * K_PAD; i += 256) {
        const int r = i / K_PAD;
        const int k = i - r * K_PAD;
        xsh[i] = (k < N_IN) ? xsrc[r * N_IN + k] : 0.0f;
    }
    const float bn = bias[n];
    __syncthreads();

    for (int rb = 0; rb < 16; ++rb) {
        const int rbase = rb << 3;
        const size_t gbase = (size_t)(r0 + rbase) * N_RNN + n;
        float npv[8];
        #pragma unroll
        for (int rr = 0; rr < 8; ++rr) npv[rr] = noise[gbase + (size_t)rr * N_RNN];
        float acc[8] = {0.f, 0.f, 0.f, 0.f, 0.f, 0.f, 0.f, 0.f};
        #pragma unroll
        for (int k4 = 0; k4 < K_PAD / 4; ++k4) {
            const float w0 = wcol[4 * k4 + 0];
            const float w1 = wcol[4 * k4 + 1];
            const float w2 = wcol[4 * k4 + 2];
            const float w3 = wcol[4 * k4 + 3];
            #pragma unroll
            for (int rr = 0; rr < 8; ++rr) {
                const float4 xv = *(const float4*)&xsh[(rbase + rr) * K_PAD + 4 * k4];
                acc[rr] = fmaf(xv.x, w0, acc[rr]);
                acc[rr] = fmaf(xv.y, w1, acc[rr]);
                acc[rr] = fmaf(xv.z, w2, acc[rr]);
                acc[rr] = fmaf(xv.w, w3, acc[rr]);
            }
        }
        #pragma unroll
        for (int rr = 0; rr < 8; ++rr) {
            G[gbase + (size_t)rr * N_RNN] = acc[rr] + bn + npv[rr];
        }
    }
}

// ---------------------------------------------------------------------------
// K3b: general W_rec fallback (block-per-b matvec). Exits immediately when
// the diagonal fast path applies.
__global__ __launch_bounds__(512) void k_scan_general(const float* __restrict__ W,
                                                      float* __restrict__ GH,
                                                      const int* __restrict__ flag) {
    if (*flag == 0) return;
    const int b = blockIdx.x;      // 128 blocks
    const int n = threadIdx.x;     // 512 threads
    const int strideT = B_SZ * N_RNN;
    float* base = GH + b * N_RNN + n;
    float h = 0.0f;
    __shared__ float hs[N_RNN];
    const float* Wr = W + N_IN * N_RNN;
    for (int t = 0; t < T_STEPS; ++t) {
        hs[n] = h;
        __syncthreads();
        float g = base[t * strideT];
        for (int k = 0; k < N_RNN; ++k) {
            g = fmaf(hs[k], Wr[k * N_RNN + n], g);
        }
        const float sp = softplus_f(g);
        h = 0.8f * h + 0.2f * sp;
        base[t * strideT] = h;
        __syncthreads();
    }
}

// ---------------------------------------------------------------------------
// K4 v2: y[row,o] = sigmoid(sum_n h[row,n]*W_out[n,o] + b_out[o])
// FOUR rows per thread: every broadcast ds_read of W_out now feeds 4 rows
// (18 LDS reads/row, was 72). Rows interleaved base+lane+64*i so h loads
// keep lane-consecutive-row coalescing / L1 line reuse across the k4 window.
// 250 blocks x 128 threads x 4 rows = 128000 rows exactly.
__global__ __launch_bounds__(128, 1) void k_head(const float* __restrict__ hbase,
                                                 const float* __restrict__ Wout,
                                                 const float* __restrict__ bout,
                                                 float* __restrict__ y) {
    __shared__ float ws[N_RNN][36];   // stride 36 keeps float4 rows 16B-aligned
    __shared__ float bs[64];
    const int tid = threadIdx.x;
    for (int i = tid; i < N_RNN * N_OUT; i += 128) {
        int k = i / N_OUT;
        int o = i - k * N_OUT;
        ws[k][o] = Wout[i];
    }
    if (tid < N_OUT) bs[tid] = bout[tid];
    __syncthreads();

    const int wid  = (blockIdx.x << 1) + (tid >> 6);   // global wave id 0..499
    const int lane = tid & 63;
    const int base = (wid << 8) + lane;                // wave covers 256 rows

    const float* hr0 = hbase + (size_t)base * N_RNN;
    const float* hr1 = hr0 + (size_t)64 * N_RNN;
    const float* hr2 = hr0 + (size_t)128 * N_RNN;
    const float* hr3 = hr0 + (size_t)192 * N_RNN;

    float acc[4][N_OUT];
    #pragma unroll
    for (int o = 0; o < N_OUT; ++o) {
        const float bo = bs[o];
        acc[0][o] = bo; acc[1][o] = bo; acc[2][o] = bo; acc[3][o] = bo;
    }

    for (int k4 = 0; k4 < N_RNN / 4; ++k4) {
        const float4 hv0 = *(const float4*)(hr0 + 4 * k4);
        const float4 hv1 = *(const float4*)(hr1 + 4 * k4);
        const float4 hv2 = *(const float4*)(hr2 + 4 * k4);
        const float4 hv3 = *(const float4*)(hr3 + 4 * k4);
        #pragma unroll
        for (int j = 0; j < 4; ++j) {
            const float hx0 = ((const float*)&hv0)[j];
            const float hx1 = ((const float*)&hv1)[j];
            const float hx2 = ((const float*)&hv2)[j];
            const float hx3 = ((const float*)&hv3)[j];
            const float* wj = &ws[4 * k4 + j][0];
            const float4* wr = (const float4*)wj;
            #pragma unroll
            for (int oo = 0; oo < 8; ++oo) {
                const float4 wv = wr[oo];               // LDS broadcast
                acc[0][4 * oo + 0] = fmaf(hx0, wv.x, acc[0][4 * oo + 0]);
                acc[0][4 * oo + 1] = fmaf(hx0, wv.y, acc[0][4 * oo + 1]);
                acc[0][4 * oo + 2] = fmaf(hx0, wv.z, acc[0][4 * oo + 2]);
                acc[0][4 * oo + 3] = fmaf(hx0, wv.w, acc[0][4 * oo + 3]);
                acc[1][4 * oo + 0] = fmaf(hx1, wv.x, acc[1][4 * oo + 0]);
                acc[1][4 * oo + 1] = fmaf(hx1, wv.y, acc[1][4 * oo + 1]);
                acc[1][4 * oo + 2] = fmaf(hx1, wv.z, acc[1][4 * oo + 2]);
                acc[1][4 * oo + 3] = fmaf(hx1, wv.w, acc[1][4 * oo + 3]);
                acc[2][4 * oo + 0] = fmaf(hx2, wv.x, acc[2][4 * oo + 0]);
                acc[2][4 * oo + 1] = fmaf(hx2, wv.y, acc[2][4 * oo + 1]);
                acc[2][4 * oo + 2] = fmaf(hx2, wv.z, acc[2][4 * oo + 2]);
                acc[2][4 * oo + 3] = fmaf(hx2, wv.w, acc[2][4 * oo + 3]);
                acc[3][4 * oo + 0] = fmaf(hx3, wv.x, acc[3][4 * oo + 0]);
                acc[3][4 * oo + 1] = fmaf(hx3, wv.y, acc[3][4 * oo + 1]);
                acc[3][4 * oo + 2] = fmaf(hx3, wv.z, acc[3][4 * oo + 2]);
                acc[3][4 * oo + 3] = fmaf(hx3, wv.w, acc[3][4 * oo + 3]);
            }
            const float w32 = wj[32];
            acc[0][32] = fmaf(hx0, w32, acc[0][32]);
            acc[1][32] = fmaf(hx1, w32, acc[1][32]);
            acc[2][32] = fmaf(hx2, w32, acc[2][32]);
            acc[3][32] = fmaf(hx3, w32, acc[3][32]);
        }
    }
    #pragma unroll
    for (int i = 0; i < 4; ++i) {
        float* yr = y + (size_t)(base + 64 * i) * N_OUT;
        #pragma unroll
        for (int o = 0; o < N_OUT; ++o) {
            yr[o] = 1.0f / (1.0f + __expf(-acc[i][o]));
        }
    }
}

// ---------------------------------------------------------------------------
extern "C" void kernel_launch(void* const* d_in, const int* in_sizes, int n_in,
                              void* d_out, int out_size, void* d_ws, size_t ws_size,
                              hipStream_t stream) {
    const float* x     = (const float*)d_in[0];  // [1000,128,85]
    const float* W     = (const float*)d_in[1];  // [597,512]
    const float* bias  = (const float*)d_in[2];  // [512]
    const float* Wout  = (const float*)d_in[3];  // [512,33]
    const float* bout  = (const float*)d_in[4];  // [33]
    const float* noise = (const float*)d_in[5];  // [1000,128,512]

    float* y  = (float*)d_out;          // y_hat region [1000,128,33]
    float* GH = y + Y_SIZE;             // h region [1000,128,512]
    int* flag = (int*)d_out;            // aliases y[0]; head overwrites it last

    k_zero_flag<<<1, 64, 0, stream>>>(flag);
    k_check_diag<<<256, 256, 0, stream>>>(W, flag);
    k_scan_fused<<<512, 64, 0, stream>>>(x, W, bias, noise, GH, flag);
    k_precompute<<<2000, 256, 0, stream>>>(x, W, bias, noise, GH, flag);  // flag!=0 only
    k_scan_general<<<128, 512, 0, stream>>>(W, GH, flag);                 // flag!=0 only
    k_head<<<250, 128, 0, stream>>>(GH, Wout, bout, y);
}